// Round 2
// 3059.706 us; speedup vs baseline: 1.0623x; 1.0623x over previous
//
#include <hip/hip_runtime.h>
#include <math.h>

#define DI __device__ __forceinline__
typedef unsigned short ush;

DI float u2f(ush u){ return __uint_as_float(((unsigned int)u)<<16); }
DI ush f2u(float f){ unsigned int u=__float_as_uint(f); u += 0x7fffu + ((u>>16)&1u); return (ush)(u>>16); }

constexpr int HWc = 4096;
constexpr float RCNT = 1.f/131072.f;      // 1 / (N*H*W)
constexpr size_t BIG = 33554432ull;       // [32][128][4096] bf16 bytes

typedef __attribute__((ext_vector_type(8))) __bf16 bf8;
typedef __attribute__((ext_vector_type(4))) float  f4;

// ---------------- K0: zero the stats block ---------------------------------
__global__ void k_zero(float* __restrict__ s){
  int i=blockIdx.x*256+threadIdx.x;
  if(i<2048) s[i]=0.f;
}

// ---------------- fallback: zero-fill output (clean diagnostic failure) ----
__global__ void k_trivial(float* __restrict__ out){
  size_t i=(size_t)blockIdx.x*256+threadIdx.x;
  if(i<16777216ull) out[i]=0.f;
}

// ---------------- K1: per-pixel channel mean/max ---------------------------
__global__ void k_chan_reduce(const float* __restrict__ x, float* __restrict__ smean, float* __restrict__ smax){
  int n = blockIdx.y;
  int px = blockIdx.x*256 + threadIdx.x;
  const float* xp = x + ((size_t)n*128)*HWc + px;
  float s=0.f, m=-INFINITY;
  #pragma unroll 8
  for(int c=0;c<128;c++){ float v=xp[(size_t)c*HWc]; s+=v; m=fmaxf(m,v); }
  smean[n*HWc+px]=s*(1.f/128.f);
  smax[n*HWc+px]=m;
}

// ---------------- K2: 7x7 conv (2->1 ch) + sigmoid -> sa -------------------
__global__ void k_sa(const float* __restrict__ smean, const float* __restrict__ smax,
                     const float* __restrict__ w, float* __restrict__ sa){
  __shared__ float wm[49], wx[49];
  int t=threadIdx.x;
  if(t<49) wm[t]=w[t];
  else if(t<98) wx[t-49]=w[t];
  __syncthreads();
  int n=blockIdx.y;
  int px=blockIdx.x*256+t;
  int r=px>>6, c=px&63;
  const float* pm  = smean + n*HWc;
  const float* pxm = smax  + n*HWc;
  float acc=0.f;
  for(int ky=0;ky<7;ky++){
    int rr=r+ky-3; if(rr<0||rr>=64) continue;
    for(int kx=0;kx<7;kx++){
      int cc=c+kx-3; if(cc<0||cc>=64) continue;
      int q=(rr<<6)+cc;
      acc += wm[ky*7+kx]*pm[q] + wx[ky*7+kx]*pxm[q];
    }
  }
  sa[n*HWc+px] = 1.f/(1.f+expf(-acc));
}

// ---------------- K3: per-(n,c) sum/max over HW of x*sa --------------------
__global__ void k_rowred(const float* __restrict__ x, const float* __restrict__ sa,
                         float* __restrict__ rsum, float* __restrict__ rmax){
  int c=blockIdx.x, n=blockIdx.y;
  const float* xp = x + ((size_t)n*128 + c)*HWc;
  const float* sp = sa + n*HWc;
  float s=0.f, m=-INFINITY;
  for(int i=threadIdx.x;i<HWc;i+=256){
    float v=xp[i]*sp[i]; s+=v; m=fmaxf(m,v);
  }
  __shared__ float ls[4], lm[4];
  for(int o=32;o>0;o>>=1){ s+=__shfl_down(s,o,64); m=fmaxf(m,__shfl_down(m,o,64)); }
  int lane=threadIdx.x&63, wv=threadIdx.x>>6;
  if(lane==0){ ls[wv]=s; lm[wv]=m; }
  __syncthreads();
  if(threadIdx.x==0){
    rsum[n*128+c]=ls[0]+ls[1]+ls[2]+ls[3];
    rmax[n*128+c]=fmaxf(fmaxf(lm[0],lm[1]),fmaxf(lm[2],lm[3]));
  }
}

// ---------------- K4a: channel-attention MLP per n -------------------------
__global__ void k_mlp(const float* __restrict__ rsum, const float* __restrict__ rmax,
                      const float* __restrict__ fc1, const float* __restrict__ fc2,
                      float* __restrict__ att){
  int n=blockIdx.x, t=threadIdx.x;
  __shared__ float zm[128], zx[128], hm[64], hx[64];
  if(t<128){ zm[t]=rsum[n*128+t]*(1.f/4096.f); zx[t]=rmax[n*128+t]; }
  __syncthreads();
  if(t<64){
    float a=0.f;
    for(int c=0;c<128;c++) a+=fc1[t*128+c]*zm[c];
    hm[t]=fmaxf(a,0.f);
  } else if(t<128){
    int j=t-64; float a=0.f;
    for(int c=0;c<128;c++) a+=fc1[j*128+c]*zx[c];
    hx[j]=fmaxf(a,0.f);
  }
  __syncthreads();
  if(t<128){
    float a=0.f,b=0.f;
    for(int j=0;j<64;j++){ float wv=fc2[t*64+j]; a+=wv*hm[j]; b+=wv*hx[j]; }
    att[n*128+t]=1.f/(1.f+expf(-(a+b)));
  }
}

// ---------------- K4b: slist, top-96, num_dict, last-occurrence map --------
__global__ void k_topk(const float* __restrict__ att, const int* __restrict__ perm,
                       int* __restrict__ nd_out, int* __restrict__ dst_pos){
  __shared__ float sl[128];
  __shared__ int nd[128];
  int t=threadIdx.x;          // 128 threads
  float s=0.f;
  for(int n=0;n<32;n++) s+=att[n*128+t];
  sl[t]=s;
  nd[t]=t;
  __syncthreads();
  float v=sl[t]; int r=0;
  for(int c=0;c<128;c++){ float u=sl[c]; r += ((u>v) || (u==v && c<t)) ? 1 : 0; }
  if(r<96) nd[r]=t;
  __syncthreads();
  if(t<32) nd[96+t]=perm[t]&127;
  __syncthreads();
  nd_out[t]=nd[t]&127;
  int pos=-1;
  for(int p=0;p<128;p++) if((nd[p]&127)==t) pos=p;
  dst_pos[t]=pos;
}

// ---------------- pool3 over an LDS-staged 64x64 plane ---------------------
DI void pool3_lds(const float* __restrict__ P, int px, float& mp, float& ap){
  int r=px>>6, c=px&63;
  float mx=-INFINITY, s=0.f; int cnt=0;
  #pragma unroll
  for(int dy=-1;dy<=1;dy++){
    int rr=r+dy; if(rr<0||rr>=64) continue;
    #pragma unroll
    for(int dx=-1;dx<=1;dx++){
      int cc=c+dx; if(cc<0||cc>=64) continue;
      float v=P[(rr<<6)+cc]; mx=fmaxf(mx,v); s+=v; cnt++;
    }
  }
  mp=mx; ap=s/(float)cnt;
}

// ---------------- K6: bn stats of max_pool3(xt), avg_pool3(xt) -------------
__global__ void k_poolstats(const float* __restrict__ x, const float* __restrict__ sa,
                            const float* __restrict__ att, const int* __restrict__ nd,
                            float* __restrict__ stats){
  int p=blockIdx.x, n=blockIdx.y, t=threadIdx.x;
  __shared__ float P[4096];
  int chs=nd[p]&127;
  float a=att[n*128+chs];
  const float* xp = x + ((size_t)n*128+chs)*HWc;
  const float* sp = sa + n*HWc;
  for(int px=t;px<HWc;px+=256) P[px]=xp[px]*sp[px]*a;
  __syncthreads();
  float sm=0,qm=0,sv=0,qv=0;
  for(int px=t;px<HWc;px+=256){
    float mp,ap; pool3_lds(P,px,mp,ap);
    sm+=mp; qm+=mp*mp; sv+=ap; qv+=ap*ap;
  }
  for(int o=32;o>0;o>>=1){
    sm+=__shfl_down(sm,o,64); qm+=__shfl_down(qm,o,64);
    sv+=__shfl_down(sv,o,64); qv+=__shfl_down(qv,o,64);
  }
  __shared__ float l[4][4];
  int lane=t&63, wv=t>>6;
  if(lane==0){ l[wv][0]=sm; l[wv][1]=qm; l[wv][2]=sv; l[wv][3]=qv; }
  __syncthreads();
  if(t==0){
    atomicAdd(&stats[p],     l[0][0]+l[1][0]+l[2][0]+l[3][0]);
    atomicAdd(&stats[128+p], l[0][1]+l[1][1]+l[2][1]+l[3][1]);
    atomicAdd(&stats[256+p], l[0][2]+l[1][2]+l[2][2]+l[3][2]);
    atomicAdd(&stats[384+p], l[0][3]+l[1][3]+l[2][3]+l[3][3]);
  }
}

// ---------------- K8a: base of output --------------------------------------
__global__ void k_base(const float* __restrict__ x, const float* __restrict__ sa,
    const float* __restrict__ att, const int* __restrict__ nd, const int* __restrict__ dpos,
    const float* __restrict__ stats, const float* __restrict__ wts, float* __restrict__ out){
  int ch=blockIdx.x, n=blockIdx.y, t=threadIdx.x;
  int p=dpos[ch];                      // block-uniform branch
  const float* sp = sa + n*HWc;
  if(p<0){
    float a=att[n*128+ch];
    const float* xp = x + ((size_t)n*128+ch)*HWc;
    float* op = out + ((size_t)n*128+ch)*HWc;
    for(int px=t;px<HWc;px+=256) op[px]=xp[px]*sp[px]*a;
    return;
  }
  p&=127;
  __shared__ float P[4096];
  int chs=nd[p]&127;
  float a=att[n*128+chs];
  const float* xp = x + ((size_t)n*128+chs)*HWc;
  for(int px=t;px<HWc;px+=256) P[px]=xp[px]*sp[px]*a;
  __syncthreads();
  float w1=wts[1],w2=wts[2],w3=wts[3];
  float m0,r0v,m1,r1v;
  { float su=stats[p],     sq=stats[128+p]; float mean=su*RCNT,var=sq*RCNT-mean*mean; m0=mean; r0v=rsqrtf(var+1e-5f); }
  { float su=stats[256+p], sq=stats[384+p]; float mean=su*RCNT,var=sq*RCNT-mean*mean; m1=mean; r1v=rsqrtf(var+1e-5f); }
  float* op = out + ((size_t)n*128+ch)*HWc;
  for(int px=t;px<HWc;px+=256){
    float mp,ap; pool3_lds(P,px,mp,ap);
    float v = w3*P[px] + w1*(mp-m0)*r0v + w2*(ap-m1)*r1v;
    op[px]=v;
  }
}

// ---------------- K_dw: depthwise conv on one (n,p) plane ------------------
template<int KS,int DIL,int PRE,int SX>
__global__ void k_dw(const float* __restrict__ xsrc, const ush* __restrict__ bufsrc,
    const float* __restrict__ dww, const float* __restrict__ stats_in,
    const float* __restrict__ sa, const float* __restrict__ att,
    const int* __restrict__ nd, ush* __restrict__ outb){
  int p=blockIdx.x, n=blockIdx.y, t=threadIdx.x;
  __shared__ float P[4096];
  const float* sp = sa + n*HWc;
  if constexpr (SX){
    int ch=nd[p]&127;
    float a=att[n*128+ch];
    const float* xp = xsrc + ((size_t)n*128+ch)*HWc;
    for(int px=t;px<HWc;px+=256) P[px]=fmaxf(xp[px]*sp[px]*a,0.f);
  } else {
    float mean=stats_in[p]*RCNT;
    float var=stats_in[128+p]*RCNT-mean*mean;
    float rstd=rsqrtf(var+1e-5f);
    const ush* bp = bufsrc + ((size_t)n*128+p)*HWc;
    for(int px=t;px<HWc;px+=256) P[px]=fmaxf((u2f(bp[px])-mean)*rstd,0.f);
  }
  __syncthreads();
  float wk[KS*KS];
  #pragma unroll
  for(int i=0;i<KS*KS;i++) wk[i]=dww[p*KS*KS+i];
  ush* op = outb + ((size_t)n*128+p)*HWc;
  for(int px=t;px<HWc;px+=256){
    int r=px>>6, c=px&63;
    float acc=0.f;
    #pragma unroll
    for(int ky=0;ky<KS;ky++){
      int rr=r+(ky-KS/2)*DIL; if(rr<0||rr>=64) continue;
      #pragma unroll
      for(int kx=0;kx<KS;kx++){
        int cc=c+(kx-KS/2)*DIL; if(cc<0||cc>=64) continue;
        acc += wk[ky*KS+kx]*P[(rr<<6)+cc];
      }
    }
    op[px]=f2u(acc);
  }
}

// ---------------- K_wcvt: f32 -> bf16 weight convert (16384 elems) ---------
__global__ void k_cvt(const float* __restrict__ src, ush* __restrict__ dst){
  int i=blockIdx.x*256+threadIdx.x;
  dst[i]=f2u(src[i]);
}

// ---------------- K_pw_mfma: pointwise 128->128 MFMA GEMM + bn stats -------
// D[co][px] = sum_ci W[co][ci] * dwin[ci][px], bf16 in, f32 acc, bf16 out.
// Block: 256 thr = 4 waves; tile M=128(co) x N=64(px), K=128 (4 steps of 32).
// B staged in LDS TRANSPOSED: Bt[px][ci] (pad +4) -> plain 8B k-contiguous
// fragment reads, the m92/m97-verified pattern. A-frags from global bf16.
__global__ __launch_bounds__(256) void k_pw_mfma(const ush* __restrict__ dwin,
    const ush* __restrict__ wt, ush* __restrict__ outb, float* __restrict__ stats){
  __shared__ ush Bt[64][132];          // 16.9 KiB, row stride 264 B
  int t=threadIdx.x, n=blockIdx.y;
  int px0b = blockIdx.x*64;

  const ush* dp = dwin + ((size_t)n*128)*HWc + px0b;
  // stage + transpose: thread handles ci pair (2*c2, 2*c2+1) x 4 px
  #pragma unroll
  for(int k=0;k<4;k++){
    int e = t + k*256;                 // [0,1024)
    int c2 = e>>4;                     // ci pair 0..63
    int p4 = (e&15)*4;                 // px 0..60 step 4
    const ush* g0 = dp + (size_t)(2*c2)*HWc + p4;
    ushort4 va = *(const ushort4*)g0;
    ushort4 vb = *(const ushort4*)(g0 + HWc);
    *(unsigned int*)&Bt[p4+0][2*c2] = (unsigned int)va.x | ((unsigned int)vb.x<<16);
    *(unsigned int*)&Bt[p4+1][2*c2] = (unsigned int)va.y | ((unsigned int)vb.y<<16);
    *(unsigned int*)&Bt[p4+2][2*c2] = (unsigned int)va.z | ((unsigned int)vb.z<<16);
    *(unsigned int*)&Bt[p4+3][2*c2] = (unsigned int)va.w | ((unsigned int)vb.w<<16);
  }

  int lane=t&63, wv=t>>6;
  int co0=(wv>>1)*64, pxw=(wv&1)*32;   // wave tile: 64 co x 32 px
  int g=lane>>4, sl=lane&15;
  // A fragments (verified layout): row(M)=co0+mt*16+sl, k=kt*32+g*8+j (j=0..7)
  int arow = co0 + sl;
  int acg  = g*8;
  bf8 a[4][4];
  #pragma unroll
  for(int mt=0;mt<4;mt++)
    #pragma unroll
    for(int kt=0;kt<4;kt++)
      a[mt][kt] = *(const bf8*)(wt + (size_t)(arow+mt*16)*128 + kt*32 + acg);

  f4 acc[4][2] = {};
  __syncthreads();

  #pragma unroll
  for(int nt=0;nt<2;nt++){
    int pxl = pxw + nt*16 + sl;        // col(N)=lane&15 within 16-px group
    bf8 b[4];
    #pragma unroll
    for(int kt=0;kt<4;kt++){
      union { uint2 h[2]; bf8 v; } u;
      const ush* bp = &Bt[pxl][kt*32 + acg];
      u.h[0] = *(const uint2*)bp;      // 8B-aligned (264*px + 64kt + 16g)
      u.h[1] = *(const uint2*)(bp+4);
      b[kt] = u.v;
    }
    #pragma unroll
    for(int kt=0;kt<4;kt++)
      #pragma unroll
      for(int mt=0;mt<4;mt++)
        acc[mt][nt] = __builtin_amdgcn_mfma_f32_16x16x32_bf16(a[mt][kt], b[kt], acc[mt][nt], 0,0,0);
  }

  // Epilogue: D layout col(px)=lane&15, row(co)=(lane>>4)*4+r. Store bf16 +
  // fused bn stats (sum, sumsq per co) via 16-lane reduce + atomics.
  #pragma unroll
  for(int mt=0;mt<4;mt++){
    #pragma unroll
    for(int r=0;r<4;r++){
      int co = co0 + mt*16 + g*4 + r;
      float v0=acc[mt][0][r], v1=acc[mt][1][r];
      ush* ob = outb + ((size_t)n*128+co)*HWc + px0b + pxw;
      ob[sl]      = f2u(v0);
      ob[16+sl]   = f2u(v1);
      float s1 = v0+v1, s2 = v0*v0+v1*v1;
      #pragma unroll
      for(int o=1;o<16;o<<=1){ s1+=__shfl_xor(s1,o,64); s2+=__shfl_xor(s2,o,64); }
      if(sl==0){ atomicAdd(&stats[co],s1); atomicAdd(&stats[128+co],s2); }
    }
  }
}

// ---------------- K8b: out += w*(br-mean)*rstd for winning positions -------
__global__ void k_accum(const ush* __restrict__ br, const int* __restrict__ nd,
    const int* __restrict__ dpos, const float* __restrict__ stats_set,
    const float* __restrict__ wts, int widx, float* __restrict__ out){
  int n=blockIdx.z, p=blockIdx.y;
  int ch=nd[p]&127;
  if(dpos[ch]!=p) return;
  int px=blockIdx.x*256+threadIdx.x;
  float su=stats_set[p], sq=stats_set[128+p];
  float mean=su*RCNT, var=sq*RCNT-mean*mean, rstd=rsqrtf(var+1e-5f);
  float w=wts[widx];
  size_t oidx=((size_t)n*128+ch)*HWc+px;
  size_t bidx=((size_t)n*128+p)*HWc+px;
  out[oidx] += w*(u2f(br[bidx])-mean)*rstd;
}

extern "C" void kernel_launch(void* const* d_in, const int* in_sizes, int n_in,
                              void* d_out, int out_size, void* d_ws, size_t ws_size,
                              hipStream_t stream){
  (void)in_sizes; (void)n_in; (void)out_size;
  const float* x   =(const float*)d_in[0];
  const float* wts =(const float*)d_in[1];
  const float* fc1 =(const float*)d_in[2];
  const float* fc2 =(const float*)d_in[3];
  const float* saw =(const float*)d_in[4];
  const float* s3d1=(const float*)d_in[5];
  const float* s3p1=(const float*)d_in[6];
  const float* s3d2=(const float*)d_in[7];
  const float* s3p2=(const float*)d_in[8];
  const float* s5d1=(const float*)d_in[9];
  const float* s5p1=(const float*)d_in[10];
  const float* s5d2=(const float*)d_in[11];
  const float* s5p2=(const float*)d_in[12];
  const float* d3dw=(const float*)d_in[13];
  const float* d3pw=(const float*)d_in[14];
  const float* d5dw=(const float*)d_in[15];
  const float* d5pw=(const float*)d_in[16];
  const int* perm=(const int*)d_in[17];
  float* out=(float*)d_out;

  char* w=(char*)d_ws;
  float* stats=(float*)w;  w+=8192;
  float* smean=(float*)w;  w+=524288;
  float* smax =(float*)w;  w+=524288;
  float* sa   =(float*)w;  w+=524288;
  float* rsum =(float*)w;  w+=16384;
  float* rmax =(float*)w;  w+=16384;
  float* att  =(float*)w;  w+=16384;
  int*   nd   =(int*)w;    w+=512;
  int*   dpos =(int*)w;    w+=512;
  size_t small_bytes=(size_t)(w-(char*)d_ws);    // 1631232
  ush* bufA=(ush*)w;
  ush* bufB=(ush*)(w+BIG);

  if(ws_size < small_bytes + 2*BIG){
    k_trivial<<<dim3(65536),dim3(256),0,stream>>>(out);
    return;
  }

  // bf16 pw weights live in the smean region (dead after k_sa). 6 x 32KB.
  ush* wb_s3p1=(ush*)smean;
  ush* wb_s3p2=wb_s3p1+16384;
  ush* wb_s5p1=wb_s3p2+16384;
  ush* wb_s5p2=wb_s5p1+16384;
  ush* wb_d3pw=wb_s5p2+16384;
  ush* wb_d5pw=wb_d3pw+16384;

  float* st2=stats+2*256;  // sep3 final
  float* st3=stats+3*256;  // sep5 final
  float* st4=stats+4*256;  // dil3
  float* st5=stats+5*256;  // dil5
  float* st6=stats+6*256;  // sep3 mid
  float* st7=stats+7*256;  // sep5 mid

  dim3 B(256);
  dim3 Gpn(128,32);        // (p, n)
  dim3 Gpw(64,32);         // (px-tile, n) for MFMA pw
  k_zero<<<dim3(8),B,0,stream>>>(stats);
  k_chan_reduce<<<dim3(16,32),B,0,stream>>>(x,smean,smax);
  k_sa<<<dim3(16,32),B,0,stream>>>(smean,smax,saw,sa);
  // smean/smax now dead -> convert pw weights into that space
  k_cvt<<<dim3(64),B,0,stream>>>(s3p1,wb_s3p1);
  k_cvt<<<dim3(64),B,0,stream>>>(s3p2,wb_s3p2);
  k_cvt<<<dim3(64),B,0,stream>>>(s5p1,wb_s5p1);
  k_cvt<<<dim3(64),B,0,stream>>>(s5p2,wb_s5p2);
  k_cvt<<<dim3(64),B,0,stream>>>(d3pw,wb_d3pw);
  k_cvt<<<dim3(64),B,0,stream>>>(d5pw,wb_d5pw);
  k_rowred<<<dim3(128,32),B,0,stream>>>(x,sa,rsum,rmax);
  k_mlp<<<dim3(32),B,0,stream>>>(rsum,rmax,fc1,fc2,att);
  k_topk<<<dim3(1),dim3(128),0,stream>>>(att,perm,nd,dpos);
  k_poolstats<<<Gpn,B,0,stream>>>(x,sa,att,nd,stats);
  k_base<<<Gpn,B,0,stream>>>(x,sa,att,nd,dpos,stats,wts,out);

  // sep3: dw1 -> pw1(st6) -> bn+relu dw2 -> pw2(st2) -> accum
  k_dw<3,1,0,1><<<Gpn,B,0,stream>>>(x,nullptr,s3d1,nullptr,sa,att,nd,bufA);
  k_pw_mfma<<<Gpw,B,0,stream>>>(bufA,wb_s3p1,bufB,st6);
  k_dw<3,1,1,0><<<Gpn,B,0,stream>>>(nullptr,bufB,s3d2,st6,sa,att,nd,bufA);
  k_pw_mfma<<<Gpw,B,0,stream>>>(bufA,wb_s3p2,bufB,st2);
  k_accum<<<dim3(16,128,32),B,0,stream>>>(bufB,nd,dpos,st2,wts,4,out);
  // sep5
  k_dw<5,1,0,1><<<Gpn,B,0,stream>>>(x,nullptr,s5d1,nullptr,sa,att,nd,bufA);
  k_pw_mfma<<<Gpw,B,0,stream>>>(bufA,wb_s5p1,bufB,st7);
  k_dw<5,1,1,0><<<Gpn,B,0,stream>>>(nullptr,bufB,s5d2,st7,sa,att,nd,bufA);
  k_pw_mfma<<<Gpw,B,0,stream>>>(bufA,wb_s5p2,bufB,st3);
  k_accum<<<dim3(16,128,32),B,0,stream>>>(bufB,nd,dpos,st3,wts,5,out);
  // dil3
  k_dw<3,2,0,1><<<Gpn,B,0,stream>>>(x,nullptr,d3dw,nullptr,sa,att,nd,bufA);
  k_pw_mfma<<<Gpw,B,0,stream>>>(bufA,wb_d3pw,bufB,st4);
  k_accum<<<dim3(16,128,32),B,0,stream>>>(bufB,nd,dpos,st4,wts,6,out);
  // dil5
  k_dw<5,2,0,1><<<Gpn,B,0,stream>>>(x,nullptr,d5dw,nullptr,sa,att,nd,bufA);
  k_pw_mfma<<<Gpw,B,0,stream>>>(bufA,wb_d5pw,bufB,st5);
  k_accum<<<dim3(16,128,32),B,0,stream>>>(bufB,nd,dpos,st5,wts,7,out);
}

// Round 3
// 775.998 us; speedup vs baseline: 4.1884x; 3.9429x over previous
//
#include <hip/hip_runtime.h>
#include <math.h>

#define DI __device__ __forceinline__
typedef unsigned short ush;

DI float u2f(ush u){ return __uint_as_float(((unsigned int)u)<<16); }
DI ush f2u(float f){ unsigned int u=__float_as_uint(f); u += 0x7fffu + ((u>>16)&1u); return (ush)(u>>16); }

constexpr int HWc = 4096;
constexpr float RCNT = 1.f/131072.f;      // 1 / (N*H*W)
constexpr size_t BIG = 33554432ull;       // [32][128][4096] bf16 bytes

typedef __attribute__((ext_vector_type(8))) __bf16 bf8;
typedef __attribute__((ext_vector_type(4))) float  f4;

// ---------------- K0: zero a float block -----------------------------------
__global__ void k_zero(float* __restrict__ s, int n){
  int i=blockIdx.x*256+threadIdx.x;
  if(i<n) s[i]=0.f;
}

// ---------------- fallback: zero-fill output (clean diagnostic failure) ----
__global__ void k_trivial(float* __restrict__ out){
  size_t i=(size_t)blockIdx.x*256+threadIdx.x;
  if(i<16777216ull) out[i]=0.f;
}

// ---------------- K1: per-pixel channel mean/max ---------------------------
__global__ void k_chan_reduce(const float* __restrict__ x, float* __restrict__ smean, float* __restrict__ smax){
  int n = blockIdx.y;
  int px = blockIdx.x*256 + threadIdx.x;
  const float* xp = x + ((size_t)n*128)*HWc + px;
  float s=0.f, m=-INFINITY;
  #pragma unroll 8
  for(int c=0;c<128;c++){ float v=xp[(size_t)c*HWc]; s+=v; m=fmaxf(m,v); }
  smean[n*HWc+px]=s*(1.f/128.f);
  smax[n*HWc+px]=m;
}

// ---------------- K2: 7x7 conv (2->1 ch) + sigmoid -> sa -------------------
__global__ void k_sa(const float* __restrict__ smean, const float* __restrict__ smax,
                     const float* __restrict__ w, float* __restrict__ sa){
  __shared__ float wm[49], wx[49];
  int t=threadIdx.x;
  if(t<49) wm[t]=w[t];
  else if(t<98) wx[t-49]=w[t];
  __syncthreads();
  int n=blockIdx.y;
  int px=blockIdx.x*256+t;
  int r=px>>6, c=px&63;
  const float* pm  = smean + n*HWc;
  const float* pxm = smax  + n*HWc;
  float acc=0.f;
  for(int ky=0;ky<7;ky++){
    int rr=r+ky-3; if(rr<0||rr>=64) continue;
    for(int kx=0;kx<7;kx++){
      int cc=c+kx-3; if(cc<0||cc>=64) continue;
      int q=(rr<<6)+cc;
      acc += wm[ky*7+kx]*pm[q] + wx[ky*7+kx]*pxm[q];
    }
  }
  sa[n*HWc+px] = 1.f/(1.f+expf(-acc));
}

// ---------------- K3: per-(n,c) sum/max over HW of x*sa --------------------
__global__ void k_rowred(const float* __restrict__ x, const float* __restrict__ sa,
                         float* __restrict__ rsum, float* __restrict__ rmax){
  int c=blockIdx.x, n=blockIdx.y;
  const float* xp = x + ((size_t)n*128 + c)*HWc;
  const float* sp = sa + n*HWc;
  float s=0.f, m=-INFINITY;
  for(int i=threadIdx.x;i<HWc;i+=256){
    float v=xp[i]*sp[i]; s+=v; m=fmaxf(m,v);
  }
  __shared__ float ls[4], lm[4];
  for(int o=32;o>0;o>>=1){ s+=__shfl_down(s,o,64); m=fmaxf(m,__shfl_down(m,o,64)); }
  int lane=threadIdx.x&63, wv=threadIdx.x>>6;
  if(lane==0){ ls[wv]=s; lm[wv]=m; }
  __syncthreads();
  if(threadIdx.x==0){
    rsum[n*128+c]=ls[0]+ls[1]+ls[2]+ls[3];
    rmax[n*128+c]=fmaxf(fmaxf(lm[0],lm[1]),fmaxf(lm[2],lm[3]));
  }
}

// ---------------- K4a: channel-attention MLP per n -------------------------
__global__ void k_mlp(const float* __restrict__ rsum, const float* __restrict__ rmax,
                      const float* __restrict__ fc1, const float* __restrict__ fc2,
                      float* __restrict__ att){
  int n=blockIdx.x, t=threadIdx.x;
  __shared__ float zm[128], zx[128], hm[64], hx[64];
  if(t<128){ zm[t]=rsum[n*128+t]*(1.f/4096.f); zx[t]=rmax[n*128+t]; }
  __syncthreads();
  if(t<64){
    float a=0.f;
    for(int c=0;c<128;c++) a+=fc1[t*128+c]*zm[c];
    hm[t]=fmaxf(a,0.f);
  } else if(t<128){
    int j=t-64; float a=0.f;
    for(int c=0;c<128;c++) a+=fc1[j*128+c]*zx[c];
    hx[j]=fmaxf(a,0.f);
  }
  __syncthreads();
  if(t<128){
    float a=0.f,b=0.f;
    for(int j=0;j<64;j++){ float wv=fc2[t*64+j]; a+=wv*hm[j]; b+=wv*hx[j]; }
    att[n*128+t]=1.f/(1.f+expf(-(a+b)));
  }
}

// ---------------- K4b: slist, top-96, num_dict, last-occurrence map --------
__global__ void k_topk(const float* __restrict__ att, const int* __restrict__ perm,
                       int* __restrict__ nd_out, int* __restrict__ dst_pos){
  __shared__ float sl[128];
  __shared__ int nd[128];
  int t=threadIdx.x;          // 128 threads
  float s=0.f;
  for(int n=0;n<32;n++) s+=att[n*128+t];
  sl[t]=s;
  nd[t]=t;
  __syncthreads();
  float v=sl[t]; int r=0;
  for(int c=0;c<128;c++){ float u=sl[c]; r += ((u>v) || (u==v && c<t)) ? 1 : 0; }
  if(r<96) nd[r]=t;
  __syncthreads();
  if(t<32) nd[96+t]=perm[t]&127;
  __syncthreads();
  nd_out[t]=nd[t]&127;
  int pos=-1;
  for(int p=0;p<128;p++) if((nd[p]&127)==t) pos=p;
  dst_pos[t]=pos;
}

// ---------------- pool3 over an LDS-staged 64x64 plane ---------------------
DI void pool3_lds(const float* __restrict__ P, int px, float& mp, float& ap){
  int r=px>>6, c=px&63;
  float mx=-INFINITY, s=0.f; int cnt=0;
  #pragma unroll
  for(int dy=-1;dy<=1;dy++){
    int rr=r+dy; if(rr<0||rr>=64) continue;
    #pragma unroll
    for(int dx=-1;dx<=1;dx++){
      int cc=c+dx; if(cc<0||cc>=64) continue;
      float v=P[(rr<<6)+cc]; mx=fmaxf(mx,v); s+=v; cnt++;
    }
  }
  mp=mx; ap=s/(float)cnt;
}

// ---------------- K6: bn stats of max_pool3(xt), avg_pool3(xt) -------------
__global__ void k_poolstats(const float* __restrict__ x, const float* __restrict__ sa,
                            const float* __restrict__ att, const int* __restrict__ nd,
                            float* __restrict__ stats){
  int p=blockIdx.x, n=blockIdx.y, t=threadIdx.x;
  __shared__ float P[4096];
  int chs=nd[p]&127;
  float a=att[n*128+chs];
  const float* xp = x + ((size_t)n*128+chs)*HWc;
  const float* sp = sa + n*HWc;
  for(int px=t;px<HWc;px+=256) P[px]=xp[px]*sp[px]*a;
  __syncthreads();
  float sm=0,qm=0,sv=0,qv=0;
  for(int px=t;px<HWc;px+=256){
    float mp,ap; pool3_lds(P,px,mp,ap);
    sm+=mp; qm+=mp*mp; sv+=ap; qv+=ap*ap;
  }
  for(int o=32;o>0;o>>=1){
    sm+=__shfl_down(sm,o,64); qm+=__shfl_down(qm,o,64);
    sv+=__shfl_down(sv,o,64); qv+=__shfl_down(qv,o,64);
  }
  __shared__ float l[4][4];
  int lane=t&63, wv=t>>6;
  if(lane==0){ l[wv][0]=sm; l[wv][1]=qm; l[wv][2]=sv; l[wv][3]=qv; }
  __syncthreads();
  if(t==0){
    atomicAdd(&stats[p],     l[0][0]+l[1][0]+l[2][0]+l[3][0]);
    atomicAdd(&stats[128+p], l[0][1]+l[1][1]+l[2][1]+l[3][1]);
    atomicAdd(&stats[256+p], l[0][2]+l[1][2]+l[2][2]+l[3][2]);
    atomicAdd(&stats[384+p], l[0][3]+l[1][3]+l[2][3]+l[3][3]);
  }
}

// ---------------- K8a: base of output --------------------------------------
__global__ void k_base(const float* __restrict__ x, const float* __restrict__ sa,
    const float* __restrict__ att, const int* __restrict__ nd, const int* __restrict__ dpos,
    const float* __restrict__ stats, const float* __restrict__ wts, float* __restrict__ out){
  int ch=blockIdx.x, n=blockIdx.y, t=threadIdx.x;
  int p=dpos[ch];                      // block-uniform branch
  const float* sp = sa + n*HWc;
  if(p<0){
    float a=att[n*128+ch];
    const float* xp = x + ((size_t)n*128+ch)*HWc;
    float* op = out + ((size_t)n*128+ch)*HWc;
    for(int px=t;px<HWc;px+=256) op[px]=xp[px]*sp[px]*a;
    return;
  }
  p&=127;
  __shared__ float P[4096];
  int chs=nd[p]&127;
  float a=att[n*128+chs];
  const float* xp = x + ((size_t)n*128+chs)*HWc;
  for(int px=t;px<HWc;px+=256) P[px]=xp[px]*sp[px]*a;
  __syncthreads();
  float w1=wts[1],w2=wts[2],w3=wts[3];
  float m0,r0v,m1,r1v;
  { float su=stats[p],     sq=stats[128+p]; float mean=su*RCNT,var=sq*RCNT-mean*mean; m0=mean; r0v=rsqrtf(var+1e-5f); }
  { float su=stats[256+p], sq=stats[384+p]; float mean=su*RCNT,var=sq*RCNT-mean*mean; m1=mean; r1v=rsqrtf(var+1e-5f); }
  float* op = out + ((size_t)n*128+ch)*HWc;
  for(int px=t;px<HWc;px+=256){
    float mp,ap; pool3_lds(P,px,mp,ap);
    float v = w3*P[px] + w1*(mp-m0)*r0v + w2*(ap-m1)*r1v;
    op[px]=v;
  }
}

// ---------------- K_dw: depthwise conv on one (n,p) plane ------------------
template<int KS,int DIL,int PRE,int SX>
__global__ void k_dw(const float* __restrict__ xsrc, const ush* __restrict__ bufsrc,
    const float* __restrict__ dww, const float* __restrict__ stats_in,
    const float* __restrict__ sa, const float* __restrict__ att,
    const int* __restrict__ nd, ush* __restrict__ outb){
  int p=blockIdx.x, n=blockIdx.y, t=threadIdx.x;
  __shared__ float P[4096];
  const float* sp = sa + n*HWc;
  if constexpr (SX){
    int ch=nd[p]&127;
    float a=att[n*128+ch];
    const float* xp = xsrc + ((size_t)n*128+ch)*HWc;
    for(int px=t;px<HWc;px+=256) P[px]=fmaxf(xp[px]*sp[px]*a,0.f);
  } else {
    float mean=stats_in[p]*RCNT;
    float var=stats_in[128+p]*RCNT-mean*mean;
    float rstd=rsqrtf(var+1e-5f);
    const ush* bp = bufsrc + ((size_t)n*128+p)*HWc;
    for(int px=t;px<HWc;px+=256) P[px]=fmaxf((u2f(bp[px])-mean)*rstd,0.f);
  }
  __syncthreads();
  float wk[KS*KS];
  #pragma unroll
  for(int i=0;i<KS*KS;i++) wk[i]=dww[p*KS*KS+i];
  ush* op = outb + ((size_t)n*128+p)*HWc;
  for(int px=t;px<HWc;px+=256){
    int r=px>>6, c=px&63;
    float acc=0.f;
    #pragma unroll
    for(int ky=0;ky<KS;ky++){
      int rr=r+(ky-KS/2)*DIL; if(rr<0||rr>=64) continue;
      #pragma unroll
      for(int kx=0;kx<KS;kx++){
        int cc=c+(kx-KS/2)*DIL; if(cc<0||cc>=64) continue;
        acc += wk[ky*KS+kx]*P[(rr<<6)+cc];
      }
    }
    op[px]=f2u(acc);
  }
}

// ---------------- K_wcvt: f32 -> bf16 weight convert (16384 elems) ---------
__global__ void k_cvt(const float* __restrict__ src, ush* __restrict__ dst){
  int i=blockIdx.x*256+threadIdx.x;
  dst[i]=f2u(src[i]);
}

// ---------------- K_statred: fold 32 stat shards into the stats slot -------
__global__ void k_statred(const float* __restrict__ shad, float* __restrict__ st){
  int t=threadIdx.x;                   // 256
  float s=0.f;
  #pragma unroll
  for(int j=0;j<32;j++) s+=shad[j*256+t];
  st[t]=s;
}

// ---------------- K_pw_mfma: pointwise 128->128 MFMA GEMM + bn stats -------
// D[co][px] = sum_ci W[co][ci] * dwin[ci][px], bf16 in, f32 acc, bf16 out.
// Block: 256 thr = 4 waves; tile M=128(co) x N=64(px), K=128 (4 steps of 32).
// B staged in LDS TRANSPOSED: Bt[px][ci] (pad +4) -> plain 8B k-contiguous
// fragment reads (m92/m97-verified pattern). A-frags from global bf16.
// bn-stats partials go to 32-way SHARDED accumulators (Guideline 12): the
// unsharded version serialized 2048 atomics/address across 8 XCDs and the
// end-of-kernel vmcnt drain made every wave wait on the jammed queue.
__global__ __launch_bounds__(256) void k_pw_mfma(const ush* __restrict__ dwin,
    const ush* __restrict__ wt, ush* __restrict__ outb, float* __restrict__ shad){
  __shared__ ush Bt[64][132];          // 16.9 KiB, row stride 264 B
  int t=threadIdx.x, n=blockIdx.y;
  int px0b = blockIdx.x*64;

  const ush* dp = dwin + ((size_t)n*128)*HWc + px0b;
  // stage + transpose: thread handles ci pair (2*c2, 2*c2+1) x 4 px
  #pragma unroll
  for(int k=0;k<4;k++){
    int e = t + k*256;                 // [0,1024)
    int c2 = e>>4;                     // ci pair 0..63
    int p4 = (e&15)*4;                 // px 0..60 step 4
    const ush* g0 = dp + (size_t)(2*c2)*HWc + p4;
    ushort4 va = *(const ushort4*)g0;
    ushort4 vb = *(const ushort4*)(g0 + HWc);
    *(unsigned int*)&Bt[p4+0][2*c2] = (unsigned int)va.x | ((unsigned int)vb.x<<16);
    *(unsigned int*)&Bt[p4+1][2*c2] = (unsigned int)va.y | ((unsigned int)vb.y<<16);
    *(unsigned int*)&Bt[p4+2][2*c2] = (unsigned int)va.z | ((unsigned int)vb.z<<16);
    *(unsigned int*)&Bt[p4+3][2*c2] = (unsigned int)va.w | ((unsigned int)vb.w<<16);
  }

  int lane=t&63, wv=t>>6;
  int co0=(wv>>1)*64, pxw=(wv&1)*32;   // wave tile: 64 co x 32 px
  int g=lane>>4, sl=lane&15;
  // A fragments (verified layout): row(M)=co0+mt*16+sl, k=kt*32+g*8+j (j=0..7)
  int arow = co0 + sl;
  int acg  = g*8;
  bf8 a[4][4];
  #pragma unroll
  for(int mt=0;mt<4;mt++)
    #pragma unroll
    for(int kt=0;kt<4;kt++)
      a[mt][kt] = *(const bf8*)(wt + (size_t)(arow+mt*16)*128 + kt*32 + acg);

  f4 acc[4][2] = {};
  __syncthreads();

  #pragma unroll
  for(int nt=0;nt<2;nt++){
    int pxl = pxw + nt*16 + sl;        // col(N)=lane&15 within 16-px group
    bf8 b[4];
    #pragma unroll
    for(int kt=0;kt<4;kt++){
      union { uint2 h[2]; bf8 v; } u;
      const ush* bp = &Bt[pxl][kt*32 + acg];
      u.h[0] = *(const uint2*)bp;      // 8B-aligned (264*px + 64kt + 16g)
      u.h[1] = *(const uint2*)(bp+4);
      b[kt] = u.v;
    }
    #pragma unroll
    for(int kt=0;kt<4;kt++)
      #pragma unroll
      for(int mt=0;mt<4;mt++)
        acc[mt][nt] = __builtin_amdgcn_mfma_f32_16x16x32_bf16(a[mt][kt], b[kt], acc[mt][nt], 0,0,0);
  }

  // Epilogue: D layout col(px)=lane&15, row(co)=(lane>>4)*4+r. Store bf16 +
  // fused bn stats (sum, sumsq per co) via 16-lane reduce + sharded atomics.
  float* sh = shad + (((blockIdx.x + blockIdx.y)&31)*256);
  #pragma unroll
  for(int mt=0;mt<4;mt++){
    #pragma unroll
    for(int r=0;r<4;r++){
      int co = co0 + mt*16 + g*4 + r;
      float v0=acc[mt][0][r], v1=acc[mt][1][r];
      ush* ob = outb + ((size_t)n*128+co)*HWc + px0b + pxw;
      ob[sl]      = f2u(v0);
      ob[16+sl]   = f2u(v1);
      float s1 = v0+v1, s2 = v0*v0+v1*v1;
      #pragma unroll
      for(int o=1;o<16;o<<=1){ s1+=__shfl_xor(s1,o,64); s2+=__shfl_xor(s2,o,64); }
      if(sl==0){ atomicAdd(&sh[co],s1); atomicAdd(&sh[128+co],s2); }
    }
  }
}

// ---------------- K8b: out += w*(br-mean)*rstd for winning positions -------
__global__ void k_accum(const ush* __restrict__ br, const int* __restrict__ nd,
    const int* __restrict__ dpos, const float* __restrict__ stats_set,
    const float* __restrict__ wts, int widx, float* __restrict__ out){
  int n=blockIdx.z, p=blockIdx.y;
  int ch=nd[p]&127;
  if(dpos[ch]!=p) return;
  int px=blockIdx.x*256+threadIdx.x;
  float su=stats_set[p], sq=stats_set[128+p];
  float mean=su*RCNT, var=sq*RCNT-mean*mean, rstd=rsqrtf(var+1e-5f);
  float w=wts[widx];
  size_t oidx=((size_t)n*128+ch)*HWc+px;
  size_t bidx=((size_t)n*128+p)*HWc+px;
  out[oidx] += w*(u2f(br[bidx])-mean)*rstd;
}

extern "C" void kernel_launch(void* const* d_in, const int* in_sizes, int n_in,
                              void* d_out, int out_size, void* d_ws, size_t ws_size,
                              hipStream_t stream){
  (void)in_sizes; (void)n_in; (void)out_size;
  const float* x   =(const float*)d_in[0];
  const float* wts =(const float*)d_in[1];
  const float* fc1 =(const float*)d_in[2];
  const float* fc2 =(const float*)d_in[3];
  const float* saw =(const float*)d_in[4];
  const float* s3d1=(const float*)d_in[5];
  const float* s3p1=(const float*)d_in[6];
  const float* s3d2=(const float*)d_in[7];
  const float* s3p2=(const float*)d_in[8];
  const float* s5d1=(const float*)d_in[9];
  const float* s5p1=(const float*)d_in[10];
  const float* s5d2=(const float*)d_in[11];
  const float* s5p2=(const float*)d_in[12];
  const float* d3dw=(const float*)d_in[13];
  const float* d3pw=(const float*)d_in[14];
  const float* d5dw=(const float*)d_in[15];
  const float* d5pw=(const float*)d_in[16];
  const int* perm=(const int*)d_in[17];
  float* out=(float*)d_out;

  char* w=(char*)d_ws;
  float* stats=(float*)w;  w+=8192;
  float* smean=(float*)w;  w+=524288;
  float* smax =(float*)w;  w+=524288;
  float* sa   =(float*)w;  w+=524288;
  float* rsum =(float*)w;  w+=16384;
  float* rmax =(float*)w;  w+=16384;
  float* att  =(float*)w;  w+=16384;
  int*   nd   =(int*)w;    w+=512;
  int*   dpos =(int*)w;    w+=512;
  size_t small_bytes=(size_t)(w-(char*)d_ws);    // 1631232
  ush* bufA=(ush*)w;
  ush* bufB=(ush*)(w+BIG);

  if(ws_size < small_bytes + 2*BIG){
    k_trivial<<<dim3(65536),dim3(256),0,stream>>>(out);
    return;
  }

  // bf16 pw weights live in the smean region (dead after k_sa). 6 x 32KB.
  ush* wb_s3p1=(ush*)smean;
  ush* wb_s3p2=wb_s3p1+16384;
  ush* wb_s5p1=wb_s3p2+16384;
  ush* wb_s5p2=wb_s5p1+16384;
  ush* wb_d3pw=wb_s5p2+16384;
  ush* wb_d5pw=wb_d3pw+16384;

  // 32-way sharded bn-stat accumulators live in smax (dead after k_sa).
  // 6 sets x 32 shards x 256 floats = 192 KB <= 512 KB.
  float* shd0=smax;            // s3p1 -> st6
  float* shd1=smax+ 8192;      // s3p2 -> st2
  float* shd2=smax+16384;      // s5p1 -> st7
  float* shd3=smax+24576;      // s5p2 -> st3
  float* shd4=smax+32768;      // d3pw -> st4
  float* shd5=smax+40960;      // d5pw -> st5

  float* st2=stats+2*256;  // sep3 final
  float* st3=stats+3*256;  // sep5 final
  float* st4=stats+4*256;  // dil3
  float* st5=stats+5*256;  // dil5
  float* st6=stats+6*256;  // sep3 mid
  float* st7=stats+7*256;  // sep5 mid

  dim3 B(256);
  dim3 Gpn(128,32);        // (p, n)
  dim3 Gpw(64,32);         // (px-tile, n) for MFMA pw
  k_zero<<<dim3(8),B,0,stream>>>(stats,2048);
  k_chan_reduce<<<dim3(16,32),B,0,stream>>>(x,smean,smax);
  k_sa<<<dim3(16,32),B,0,stream>>>(smean,smax,saw,sa);
  // smean/smax now dead -> weights + stat shards live there
  k_zero<<<dim3(192),B,0,stream>>>(smax,49152);
  k_cvt<<<dim3(64),B,0,stream>>>(s3p1,wb_s3p1);
  k_cvt<<<dim3(64),B,0,stream>>>(s3p2,wb_s3p2);
  k_cvt<<<dim3(64),B,0,stream>>>(s5p1,wb_s5p1);
  k_cvt<<<dim3(64),B,0,stream>>>(s5p2,wb_s5p2);
  k_cvt<<<dim3(64),B,0,stream>>>(d3pw,wb_d3pw);
  k_cvt<<<dim3(64),B,0,stream>>>(d5pw,wb_d5pw);
  k_rowred<<<dim3(128,32),B,0,stream>>>(x,sa,rsum,rmax);
  k_mlp<<<dim3(32),B,0,stream>>>(rsum,rmax,fc1,fc2,att);
  k_topk<<<dim3(1),dim3(128),0,stream>>>(att,perm,nd,dpos);
  k_poolstats<<<Gpn,B,0,stream>>>(x,sa,att,nd,stats);
  k_base<<<Gpn,B,0,stream>>>(x,sa,att,nd,dpos,stats,wts,out);

  // sep3: dw1 -> pw1(st6) -> bn+relu dw2 -> pw2(st2) -> accum
  k_dw<3,1,0,1><<<Gpn,B,0,stream>>>(x,nullptr,s3d1,nullptr,sa,att,nd,bufA);
  k_pw_mfma<<<Gpw,B,0,stream>>>(bufA,wb_s3p1,bufB,shd0);
  k_statred<<<dim3(1),B,0,stream>>>(shd0,st6);
  k_dw<3,1,1,0><<<Gpn,B,0,stream>>>(nullptr,bufB,s3d2,st6,sa,att,nd,bufA);
  k_pw_mfma<<<Gpw,B,0,stream>>>(bufA,wb_s3p2,bufB,shd1);
  k_statred<<<dim3(1),B,0,stream>>>(shd1,st2);
  k_accum<<<dim3(16,128,32),B,0,stream>>>(bufB,nd,dpos,st2,wts,4,out);
  // sep5
  k_dw<5,1,0,1><<<Gpn,B,0,stream>>>(x,nullptr,s5d1,nullptr,sa,att,nd,bufA);
  k_pw_mfma<<<Gpw,B,0,stream>>>(bufA,wb_s5p1,bufB,shd2);
  k_statred<<<dim3(1),B,0,stream>>>(shd2,st7);
  k_dw<5,1,1,0><<<Gpn,B,0,stream>>>(nullptr,bufB,s5d2,st7,sa,att,nd,bufA);
  k_pw_mfma<<<Gpw,B,0,stream>>>(bufA,wb_s5p2,bufB,shd3);
  k_statred<<<dim3(1),B,0,stream>>>(shd3,st3);
  k_accum<<<dim3(16,128,32),B,0,stream>>>(bufB,nd,dpos,st3,wts,5,out);
  // dil3
  k_dw<3,2,0,1><<<Gpn,B,0,stream>>>(x,nullptr,d3dw,nullptr,sa,att,nd,bufA);
  k_pw_mfma<<<Gpw,B,0,stream>>>(bufA,wb_d3pw,bufB,shd4);
  k_statred<<<dim3(1),B,0,stream>>>(shd4,st4);
  k_accum<<<dim3(16,128,32),B,0,stream>>>(bufB,nd,dpos,st4,wts,6,out);
  // dil5
  k_dw<5,2,0,1><<<Gpn,B,0,stream>>>(x,nullptr,d5dw,nullptr,sa,att,nd,bufA);
  k_pw_mfma<<<Gpw,B,0,stream>>>(bufA,wb_d5pw,bufB,shd5);
  k_statred<<<dim3(1),B,0,stream>>>(shd5,st5);
  k_accum<<<dim3(16,128,32),B,0,stream>>>(bufB,nd,dpos,st5,wts,7,out);
}